// Round 4
// baseline (379.269 us; speedup 1.0000x reference)
//
#include <hip/hip_runtime.h>

// Per-image standardization, input (64, 512, 512, 3) fp32.
//
// Fused single kernel, FLUSH-FREE per-image sync, REGULAR cached stores.
//
// History/evidence:
//  r0: two kernels, NT stores      -> ~140 us kernel-time (dur 360)
//  r1: cg::grid.sync fused, NT     -> 233 us (ideal traffic, 1.7 TB/s)
//  r2: acq/rel spin fused, NT      -> 367 us (WRITE +25 MB)
//  r3: relaxed-spin fused, NT      -> 150 us, WRITE +25 MB (=1/8 array),
//                                     implied write BW ~2 TB/s
// Theory r4: __builtin_nontemporal_store is the phase-2 bottleneck —
// write-through/no-allocate path streams at ~2 TB/s and emits +1/8
// partial-line traffic, vs 6.6 TB/s for ordinary cached stores (proven by
// the harness's own fillBuffer dispatches). Regular stores do write-
// allocate and will evict some L3-resident input, but that costs at most
// ~30 us of re-fetch vs ~70 us of write-throughput loss.
//
// Sync design (kept from r3): all cross-block control data via RELAXED
// agent-scope atomics (no L2 wb/inv maintenance ops); producer ordering by
// s_waitcnt vmcnt(0); last-arriving block computes per-image stats once.
//
// Geometry: 64 images x 32 blocks/image = 2048 blocks x 256 threads,
// __launch_bounds__(256, 8): whole grid co-resident (256 CU x 8 blocks),
// so the per-image wait cannot deadlock regardless of dispatch order.

#define N_IMG 64
#define ELEMS_PER_IMG 786432
#define VEC4_PER_IMG 196608
#define BLOCKS_PER_IMG 32
#define GRID (N_IMG * BLOCKS_PER_IMG)                    // 2048
#define THREADS 256
#define VEC4_PER_BLOCK (VEC4_PER_IMG / BLOCKS_PER_IMG)   // 6144
#define VEC4_PER_THREAD (VEC4_PER_BLOCK / THREADS)       // 24

// ws layout:
//   [0, 8 KiB):  per-image control lines, 128 B apart (memset to 0):
//                int[0]=arrival ctr, int[1]=stats flag,
//                int[2]=mean bits,   int[3]=inv-stddev bits
//   [8 KiB, 24 KiB): 2048 x {sum, sumsq} partials (guarded by ctr, no clear)
#define CTRL_INTS_PER_IMG 32   // 128 B stride

typedef float v4f __attribute__((ext_vector_type(4)));

__device__ __forceinline__ void waitcnt_vm0() {
    asm volatile("s_waitcnt vmcnt(0)" ::: "memory");
}

__global__ __launch_bounds__(THREADS, 8) void std_fused_nf(
    const v4f* __restrict__ in, v4f* __restrict__ out,
    int* __restrict__ ctrl, float* __restrict__ partials) {
    const int img = blockIdx.x >> 5;          // / BLOCKS_PER_IMG
    const int blk = blockIdx.x & 31;          // % BLOCKS_PER_IMG
    const size_t base =
        (size_t)img * VEC4_PER_IMG + (size_t)blk * VEC4_PER_BLOCK;
    const v4f* __restrict__ bin = in + base;

    // ---- phase 1: partial {sum, sumsq} for this block's chunk ----
    float s = 0.f, sq = 0.f;
#pragma unroll
    for (int i = 0; i < VEC4_PER_THREAD; ++i) {
        v4f v = bin[threadIdx.x + i * THREADS];  // cached: warms L2/L3
        s += (v.x + v.y) + (v.z + v.w);
        sq = fmaf(v.x, v.x, sq);
        sq = fmaf(v.y, v.y, sq);
        sq = fmaf(v.z, v.z, sq);
        sq = fmaf(v.w, v.w, sq);
    }
#pragma unroll
    for (int off = 32; off > 0; off >>= 1) {
        s += __shfl_down(s, off);
        sq += __shfl_down(sq, off);
    }

    __shared__ float ss[4], ssq[4];
    __shared__ int s_last;
    __shared__ float s_mean, s_inv;
    const int lane = threadIdx.x & 63;
    const int wave = threadIdx.x >> 6;
    if (lane == 0) { ss[wave] = s; ssq[wave] = sq; }
    __syncthreads();

    int* line = ctrl + img * CTRL_INTS_PER_IMG;
    float* stats = (float*)(line + 2);

    // ---- publish partial + arrive (all relaxed, zero cache maintenance) ----
    if (threadIdx.x == 0) {
        const float ps = (ss[0] + ss[1]) + (ss[2] + ss[3]);
        const float pq = (ssq[0] + ssq[1]) + (ssq[2] + ssq[3]);
        __hip_atomic_store(&partials[2 * blockIdx.x + 0], ps,
                           __ATOMIC_RELAXED, __HIP_MEMORY_SCOPE_AGENT);
        __hip_atomic_store(&partials[2 * blockIdx.x + 1], pq,
                           __ATOMIC_RELAXED, __HIP_MEMORY_SCOPE_AGENT);
        waitcnt_vm0();  // partial is at the coherence point before we arrive
        const int old = __hip_atomic_fetch_add(line, 1, __ATOMIC_RELAXED,
                                               __HIP_MEMORY_SCOPE_AGENT);
        s_last = (old == BLOCKS_PER_IMG - 1);
    }
    __syncthreads();

    if (s_last) {
        // Last-arriving block: all 32 partials are complete. Wave 0 reduces
        // them in parallel and publishes {mean, inv} once for the image.
        float ps = 0.f, pq = 0.f;
        if (threadIdx.x < BLOCKS_PER_IMG) {
            const int pi = 2 * (img * BLOCKS_PER_IMG + threadIdx.x);
            ps = __hip_atomic_load(&partials[pi + 0], __ATOMIC_RELAXED,
                                   __HIP_MEMORY_SCOPE_AGENT);
            pq = __hip_atomic_load(&partials[pi + 1], __ATOMIC_RELAXED,
                                   __HIP_MEMORY_SCOPE_AGENT);
        }
        if (threadIdx.x < 64) {  // whole wave 0 participates in shuffles
#pragma unroll
            for (int off = 16; off > 0; off >>= 1) {
                ps += __shfl_down(ps, off);
                pq += __shfl_down(pq, off);
            }
            if (threadIdx.x == 0) {
                const float invN = 1.0f / (float)ELEMS_PER_IMG;
                const float mean = ps * invN;
                const float var = fmaxf(pq * invN - mean * mean, 0.0f);
                const float min_sd = 1.0f / sqrtf((float)ELEMS_PER_IMG);
                const float sd = fmaxf(sqrtf(var), min_sd);  // TF clamp
                const float inv = 1.0f / sd;
                s_mean = mean;
                s_inv = inv;
                __hip_atomic_store(&stats[0], mean, __ATOMIC_RELAXED,
                                   __HIP_MEMORY_SCOPE_AGENT);
                __hip_atomic_store(&stats[1], inv, __ATOMIC_RELAXED,
                                   __HIP_MEMORY_SCOPE_AGENT);
                waitcnt_vm0();  // stats visible before the flag
                __hip_atomic_store(line + 1, 1, __ATOMIC_RELAXED,
                                   __HIP_MEMORY_SCOPE_AGENT);
            }
        }
    } else {
        // One thread waits on the 1-word flag (relaxed load: no cache ops),
        // then reads the 2 published stats words.
        if (threadIdx.x == 0) {
            while (__hip_atomic_load(line + 1, __ATOMIC_RELAXED,
                                     __HIP_MEMORY_SCOPE_AGENT) == 0) {
                __builtin_amdgcn_s_sleep(2);
            }
            asm volatile("" ::: "memory");  // don't hoist stats loads
            s_mean = __hip_atomic_load(&stats[0], __ATOMIC_RELAXED,
                                       __HIP_MEMORY_SCOPE_AGENT);
            s_inv = __hip_atomic_load(&stats[1], __ATOMIC_RELAXED,
                                      __HIP_MEMORY_SCOPE_AGENT);
        }
    }
    __syncthreads();
    const float mean = s_mean;
    const float inv = s_inv;

    // ---- phase 2: normalize chunk. Re-read is L2/L3-served (r3 FETCH
    // proof). REGULAR cached stores: the fill kernels prove this path
    // sustains 6.6 TB/s, vs ~2 TB/s observed for nontemporal stores. ----
    v4f* __restrict__ bout = out + base;
#pragma unroll
    for (int i = 0; i < VEC4_PER_THREAD; ++i) {
        const int idx = threadIdx.x + i * THREADS;
        v4f v = bin[idx];
        v4f r;
        r.x = (v.x - mean) * inv;
        r.y = (v.y - mean) * inv;
        r.z = (v.z - mean) * inv;
        r.w = (v.w - mean) * inv;
        bout[idx] = r;
    }
}

extern "C" void kernel_launch(void* const* d_in, const int* in_sizes, int n_in,
                              void* d_out, int out_size, void* d_ws, size_t ws_size,
                              hipStream_t stream) {
    const v4f* in = (const v4f*)d_in[0];
    v4f* out = (v4f*)d_out;
    int* ctrl = (int*)d_ws;                             // 8 KiB, zeroed
    float* partials = (float*)((char*)d_ws + 8192);     // 16 KiB, guarded

    hipMemsetAsync(ctrl, 0, N_IMG * CTRL_INTS_PER_IMG * sizeof(int), stream);
    std_fused_nf<<<GRID, THREADS, 0, stream>>>(in, out, ctrl, partials);
}

// Round 5
// 366.248 us; speedup vs baseline: 1.0356x; 1.0356x over previous
//
#include <hip/hip_runtime.h>

// Per-image standardization, input (64, 512, 512, 3) fp32.
//
// PERSISTENT register-resident kernel: data crosses the mean-sync in VGPRs,
// so the input is read from HBM exactly ONCE and never re-read.
//
// History/evidence:
//  r0: two kernels, NT stores       -> ~140 us kernel (dur 360)
//  r1: cg::grid.sync fused, NT      -> 234 us (clean 403 MB, 1.7 TB/s)
//  r2: acq/rel spin fused, NT       -> 367 us (L2 wb/inv storm)
//  r3: relaxed-spin fused, NT       -> 150 us  <- best so far
//  r4: relaxed-spin fused, cached   -> 160 us; WRITE inflation unchanged
//      => store type exonerated; NT slightly better; inflation is
//         sync-attached. Remaining structural cost: input read twice
//         (HBM + MALL round-trip) and lockstep phase bursts.
// r5 (this): persistent 1024-block grid, 4 rounds x 16 images. Per round
// each block loads its chunk into REGISTERS (12 x float4 = 48 VGPRs),
// reduces, does the flush-free per-image sync (relaxed agent atomics only,
// float atomicAdd accumulators), then normalizes FROM REGISTERS + NT store.
// Round r+1 reads overlap round r writes -> mixed streams, staggered syncs.
//
// Co-residency: __launch_bounds__(256, 4) caps VGPR at 128 -> 4 blocks/CU
// guaranteed -> all 1024 blocks resident from t=0. The per-image wait is
// deadlock-free with NO dispatch-order assumptions.

#define N_IMG 64
#define ELEMS_PER_IMG 786432
#define VEC4_PER_IMG 196608
#define THREADS 256
#define GRID 1024
#define ROUNDS 4
#define IMGS_PER_ROUND 16          // = GRID / BLOCKS_PER_IMG
#define BLOCKS_PER_IMG 64
#define VEC4_PER_CHUNK 3072        // = VEC4_PER_IMG / BLOCKS_PER_IMG
#define VEC4_PER_THREAD 12         // = VEC4_PER_CHUNK / THREADS

// ws: 64 images x 128-B control line (memset to 0 each launch):
//   int[0]=arrival ctr, int[1]=stats flag,
//   float[2]=sum acc, float[3]=sumsq acc, float[4]=mean, float[5]=inv
#define CTRL_INTS_PER_IMG 32

typedef float v4f __attribute__((ext_vector_type(4)));

__device__ __forceinline__ void waitcnt_vm0() {
    asm volatile("s_waitcnt vmcnt(0)" ::: "memory");
}

__global__ __launch_bounds__(THREADS, 4) void std_persist(
    const v4f* __restrict__ in, v4f* __restrict__ out,
    int* __restrict__ ctrl) {
    const int sb = blockIdx.x & (BLOCKS_PER_IMG - 1);
    const int gslot = blockIdx.x >> 6;   // 0..15: image slot within a round

    __shared__ float ss[4], ssq[4];
    __shared__ float s_mean, s_inv;
    const int lane = threadIdx.x & 63;
    const int wave = threadIdx.x >> 6;

    for (int r = 0; r < ROUNDS; ++r) {
        const int img = r * IMGS_PER_ROUND + gslot;
        const size_t base =
            (size_t)img * VEC4_PER_IMG + (size_t)sb * VEC4_PER_CHUNK;
        const v4f* __restrict__ bin = in + base;

        // ---- load chunk into registers (stays live across the sync) ----
        v4f d[VEC4_PER_THREAD];
#pragma unroll
        for (int i = 0; i < VEC4_PER_THREAD; ++i) {
            d[i] = bin[threadIdx.x + i * THREADS];   // coalesced, 12 in flight
        }
        float s = 0.f, sq = 0.f;
#pragma unroll
        for (int i = 0; i < VEC4_PER_THREAD; ++i) {
            const v4f v = d[i];
            s += (v.x + v.y) + (v.z + v.w);
            sq = fmaf(v.x, v.x, sq);
            sq = fmaf(v.y, v.y, sq);
            sq = fmaf(v.z, v.z, sq);
            sq = fmaf(v.w, v.w, sq);
        }
#pragma unroll
        for (int off = 32; off > 0; off >>= 1) {
            s += __shfl_down(s, off);
            sq += __shfl_down(sq, off);
        }
        if (lane == 0) { ss[wave] = s; ssq[wave] = sq; }
        __syncthreads();

        // ---- flush-free per-image sync (relaxed agent atomics only) ----
        int* line = ctrl + img * CTRL_INTS_PER_IMG;
        float* acc = (float*)(line + 2);
        float* stats = (float*)(line + 4);
        if (threadIdx.x == 0) {
            const float bs = (ss[0] + ss[1]) + (ss[2] + ss[3]);
            const float bq = (ssq[0] + ssq[1]) + (ssq[2] + ssq[3]);
            __hip_atomic_fetch_add(&acc[0], bs, __ATOMIC_RELAXED,
                                   __HIP_MEMORY_SCOPE_AGENT);
            __hip_atomic_fetch_add(&acc[1], bq, __ATOMIC_RELAXED,
                                   __HIP_MEMORY_SCOPE_AGENT);
            waitcnt_vm0();  // adds complete at coherence point before arrival
            const int old = __hip_atomic_fetch_add(line, 1, __ATOMIC_RELAXED,
                                                   __HIP_MEMORY_SCOPE_AGENT);
            if (old == BLOCKS_PER_IMG - 1) {
                // Last arriver: all 64 adds are globally complete.
                const float ts = __hip_atomic_load(&acc[0], __ATOMIC_RELAXED,
                                                   __HIP_MEMORY_SCOPE_AGENT);
                const float tq = __hip_atomic_load(&acc[1], __ATOMIC_RELAXED,
                                                   __HIP_MEMORY_SCOPE_AGENT);
                const float invN = 1.0f / (float)ELEMS_PER_IMG;
                const float mean = ts * invN;
                const float var = fmaxf(tq * invN - mean * mean, 0.0f);
                const float min_sd = 1.0f / sqrtf((float)ELEMS_PER_IMG);
                const float sd = fmaxf(sqrtf(var), min_sd);  // TF clamp
                const float inv = 1.0f / sd;
                s_mean = mean;
                s_inv = inv;
                __hip_atomic_store(&stats[0], mean, __ATOMIC_RELAXED,
                                   __HIP_MEMORY_SCOPE_AGENT);
                __hip_atomic_store(&stats[1], inv, __ATOMIC_RELAXED,
                                   __HIP_MEMORY_SCOPE_AGENT);
                waitcnt_vm0();  // stats at coherence point before the flag
                __hip_atomic_store(line + 1, 1, __ATOMIC_RELAXED,
                                   __HIP_MEMORY_SCOPE_AGENT);
            } else {
                while (__hip_atomic_load(line + 1, __ATOMIC_RELAXED,
                                         __HIP_MEMORY_SCOPE_AGENT) == 0) {
                    __builtin_amdgcn_s_sleep(8);  // gentle poll, ~0.2 us
                }
                asm volatile("" ::: "memory");  // don't hoist stats loads
                s_mean = __hip_atomic_load(&stats[0], __ATOMIC_RELAXED,
                                           __HIP_MEMORY_SCOPE_AGENT);
                s_inv = __hip_atomic_load(&stats[1], __ATOMIC_RELAXED,
                                          __HIP_MEMORY_SCOPE_AGENT);
            }
        }
        __syncthreads();
        const float mean = s_mean;
        const float inv = s_inv;

        // ---- normalize FROM REGISTERS, NT store (r3: NT > cached here) ----
        v4f* __restrict__ bout = out + base;
#pragma unroll
        for (int i = 0; i < VEC4_PER_THREAD; ++i) {
            const v4f v = d[i];
            v4f o;
            o.x = (v.x - mean) * inv;
            o.y = (v.y - mean) * inv;
            o.z = (v.z - mean) * inv;
            o.w = (v.w - mean) * inv;
            __builtin_nontemporal_store(o, &bout[threadIdx.x + i * THREADS]);
        }
        // No extra barrier needed: next round's ss/ssq write is fenced by
        // this round's post-sync __syncthreads (all waves consumed s_mean
        // before any wave can reach next round's first __syncthreads).
    }
}

extern "C" void kernel_launch(void* const* d_in, const int* in_sizes, int n_in,
                              void* d_out, int out_size, void* d_ws, size_t ws_size,
                              hipStream_t stream) {
    const v4f* in = (const v4f*)d_in[0];
    v4f* out = (v4f*)d_out;
    int* ctrl = (int*)d_ws;  // 64 x 128 B = 8 KiB

    hipMemsetAsync(ctrl, 0, N_IMG * CTRL_INTS_PER_IMG * sizeof(int), stream);
    std_persist<<<GRID, THREADS, 0, stream>>>(in, out, ctrl);
}